// Round 22
// baseline (349.683 us; speedup 1.0000x reference)
//
#include <hip/hip_runtime.h>

// R22: production = R21 (best, 54.5us) with scatter AMPLIFIED x8, plus a
// SHADOW scatter variant (NSUB=16 -> 2 blocks/CU) amplified x8 into scratch.
// Within-probe A/B: both variants' per-rep cost + counters in one round.
// R23 ships the winner with reps=1.

#define NMOL   32
#define NATOM  512
#define NPAIR  32768
#define NB     64
#define HIDDEN 256
#define TOTNATOM (NMOL * NATOM)
#define NSUB   8
#define BLKCAP 2560
#define ABLK   8
#define SLOTS  128
#define SREP   8

// shadow variant params
#define NSUB2   16
#define BLKCAP2 1280

typedef __attribute__((ext_vector_type(8))) short bf16x8;
typedef __attribute__((ext_vector_type(4))) float f32x4;

__device__ __forceinline__ unsigned short f2bf(float x) {   // RNE f32->bf16
    unsigned u = __float_as_uint(x);
    u += 0x7FFFu + ((u >> 16) & 1u);
    return (unsigned short)(u >> 16);
}

// ---------------------------------------------------------------------------
// K1 scatter (production, NSUB=8, 256 blocks = 1 block/CU), reps x amplified.
// ---------------------------------------------------------------------------
__global__ __launch_bounds__(1024) void scatter_kernel(
    const float* __restrict__ cart, const float* __restrict__ shifts,
    const int* __restrict__ species, const int* __restrict__ atom_index,
    unsigned* __restrict__ cnt, unsigned* __restrict__ soff_g,
    float2* __restrict__ rec, float* __restrict__ tv_part,
    float* __restrict__ dipole, int ndip, int reps)
{
    __shared__ float    tv_sc[NATOM * 3];
    __shared__ float    s_cart[NATOM * 3];
    __shared__ int      s_sp[NATOM];
    __shared__ unsigned lcnt[NATOM];
    __shared__ unsigned inc[NATOM];
    __shared__ unsigned pcnt[NATOM];
    __shared__ float2   list[BLKCAP];

    const int tid = threadIdx.x;
    const int b   = blockIdx.x;
    const int mol = b >> 3;
    const int sub = b & 7;

    if (b == 0 && tid < ndip) dipole[tid] = 0.f;

    const float* cm = cart + (size_t)mol * NATOM * 3;
    const int*   sp = species + (size_t)mol * NATOM;
    for (int i = tid; i < NATOM * 3; i += 1024) s_cart[i] = cm[i];   // RO, once
    if (tid < NATOM) s_sp[tid] = sp[tid];

    const int* ai0 = atom_index + (size_t)mol * NPAIR;
    const int* ai1 = ai0 + (size_t)NMOL * NPAIR;
    const float* sh = shifts + (size_t)mol * NPAIR * 3;
    const int base = sub * 4096;

    for (int rep = 0; rep < reps; ++rep) {
        __syncthreads();
        for (int i = tid; i < NATOM * 3; i += 1024) tv_sc[i] = 0.f;
        if (tid < NATOM) { lcnt[tid] = 0u; pcnt[tid] = 0u; }
        __syncthreads();

        float    rd[4];
        unsigned rf[4];
        int      ri[4];
#pragma unroll
        for (int k = 0; k < 4; ++k) {
            ri[k] = -1;
            const int p  = base + k * 1024 + tid;
            const int i0 = ai0[p];
            const int i1 = ai1[p];
            const float sx = sh[p * 3 + 0], sy = sh[p * 3 + 1], sz = sh[p * 3 + 2];
            if (!(sx > -1e10f && sy > -1e10f && sz > -1e10f)) continue;
            const float dx = s_cart[i0 * 3 + 0] - s_cart[i1 * 3 + 0] + sx;
            const float dy = s_cart[i0 * 3 + 1] - s_cart[i1 * 3 + 1] + sy;
            const float dz = s_cart[i0 * 3 + 2] - s_cart[i1 * 3 + 2] + sz;
            unsafeAtomicAdd(&tv_sc[i0 * 3 + 0], dx);
            unsafeAtomicAdd(&tv_sc[i0 * 3 + 1], dy);
            unsafeAtomicAdd(&tv_sc[i0 * 3 + 2], dz);
            const float d = sqrtf(dx * dx + dy * dy + dz * dz + 1e-12f);
            if (d < 5.0f) {
                const float fc = 0.5f * (__cosf(0.62831853071795864769f * d) + 1.f);
                rd[k] = d;
                rf[k] = (__float_as_uint(fc) & ~7u) | (unsigned)s_sp[i1];
                ri[k] = i0;
                atomicAdd(&lcnt[i0], 1u);
            }
        }
        __syncthreads();

        if (tid < NATOM) inc[tid] = lcnt[tid];
        __syncthreads();
#pragma unroll
        for (int off = 1; off < NATOM; off <<= 1) {
            unsigned v = 0;
            if (tid < NATOM && tid >= off) v = inc[tid - off];
            __syncthreads();
            if (tid < NATOM) inc[tid] += v;
            __syncthreads();
        }

#pragma unroll
        for (int k = 0; k < 4; ++k) {
            if (ri[k] >= 0) {
                const unsigned exc = inc[ri[k]] - lcnt[ri[k]];
                const unsigned pos = atomicAdd(&pcnt[ri[k]], 1u);
                const unsigned idx = exc + pos;
                if (idx < (unsigned)BLKCAP)
                    list[idx] = make_float2(rd[k], __uint_as_float(rf[k]));
            }
        }
        __syncthreads();

        const int tot = min((int)inc[NATOM - 1], BLKCAP);
        float2* dstr = rec + (size_t)b * BLKCAP;
        for (int i = tid; i < tot; i += 1024) dstr[i] = list[i];
        if (tid < NATOM) {
            cnt[((size_t)mol * NATOM + tid) * NSUB + sub] = lcnt[tid];
            soff_g[(size_t)b * NATOM + tid] = inc[tid] - lcnt[tid];
        }
        float* tg = tv_part + (size_t)b * NATOM * 3;
        for (int i = tid; i < NATOM * 3; i += 1024) tg[i] = tv_sc[i];
    }
}

// ---------------------------------------------------------------------------
// K1b scatter16 (SHADOW, NSUB=16, 512 blocks = 2 blocks/CU, 30KB LDS),
// reps x amplified, writes to scratch only. Tests the occupancy hypothesis.
// ---------------------------------------------------------------------------
__global__ __launch_bounds__(1024) void scatter16_kernel(
    const float* __restrict__ cart, const float* __restrict__ shifts,
    const int* __restrict__ species, const int* __restrict__ atom_index,
    unsigned* __restrict__ cnt, unsigned* __restrict__ soff_g,
    float2* __restrict__ rec, float* __restrict__ tv_part, int reps)
{
    __shared__ float    tv_sc[NATOM * 3];
    __shared__ float    s_cart[NATOM * 3];
    __shared__ int      s_sp[NATOM];
    __shared__ unsigned lcnt[NATOM];
    __shared__ unsigned inc[NATOM];
    __shared__ unsigned pcnt[NATOM];
    __shared__ float2   list[BLKCAP2];      // 10 KB -> total 30 KB

    const int tid = threadIdx.x;
    const int b   = blockIdx.x;
    const int mol = b >> 4;
    const int sub = b & 15;

    const float* cm = cart + (size_t)mol * NATOM * 3;
    const int*   sp = species + (size_t)mol * NATOM;
    for (int i = tid; i < NATOM * 3; i += 1024) s_cart[i] = cm[i];
    if (tid < NATOM) s_sp[tid] = sp[tid];

    const int* ai0 = atom_index + (size_t)mol * NPAIR;
    const int* ai1 = ai0 + (size_t)NMOL * NPAIR;
    const float* sh = shifts + (size_t)mol * NPAIR * 3;
    const int base = sub * 2048;

    for (int rep = 0; rep < reps; ++rep) {
        __syncthreads();
        for (int i = tid; i < NATOM * 3; i += 1024) tv_sc[i] = 0.f;
        if (tid < NATOM) { lcnt[tid] = 0u; pcnt[tid] = 0u; }
        __syncthreads();

        float    rd[2];
        unsigned rf[2];
        int      ri[2];
#pragma unroll
        for (int k = 0; k < 2; ++k) {
            ri[k] = -1;
            const int p  = base + k * 1024 + tid;
            const int i0 = ai0[p];
            const int i1 = ai1[p];
            const float sx = sh[p * 3 + 0], sy = sh[p * 3 + 1], sz = sh[p * 3 + 2];
            if (!(sx > -1e10f && sy > -1e10f && sz > -1e10f)) continue;
            const float dx = s_cart[i0 * 3 + 0] - s_cart[i1 * 3 + 0] + sx;
            const float dy = s_cart[i0 * 3 + 1] - s_cart[i1 * 3 + 1] + sy;
            const float dz = s_cart[i0 * 3 + 2] - s_cart[i1 * 3 + 2] + sz;
            unsafeAtomicAdd(&tv_sc[i0 * 3 + 0], dx);
            unsafeAtomicAdd(&tv_sc[i0 * 3 + 1], dy);
            unsafeAtomicAdd(&tv_sc[i0 * 3 + 2], dz);
            const float d = sqrtf(dx * dx + dy * dy + dz * dz + 1e-12f);
            if (d < 5.0f) {
                const float fc = 0.5f * (__cosf(0.62831853071795864769f * d) + 1.f);
                rd[k] = d;
                rf[k] = (__float_as_uint(fc) & ~7u) | (unsigned)s_sp[i1];
                ri[k] = i0;
                atomicAdd(&lcnt[i0], 1u);
            }
        }
        __syncthreads();

        if (tid < NATOM) inc[tid] = lcnt[tid];
        __syncthreads();
#pragma unroll
        for (int off = 1; off < NATOM; off <<= 1) {
            unsigned v = 0;
            if (tid < NATOM && tid >= off) v = inc[tid - off];
            __syncthreads();
            if (tid < NATOM) inc[tid] += v;
            __syncthreads();
        }

#pragma unroll
        for (int k = 0; k < 2; ++k) {
            if (ri[k] >= 0) {
                const unsigned exc = inc[ri[k]] - lcnt[ri[k]];
                const unsigned pos = atomicAdd(&pcnt[ri[k]], 1u);
                const unsigned idx = exc + pos;
                if (idx < (unsigned)BLKCAP2)
                    list[idx] = make_float2(rd[k], __uint_as_float(rf[k]));
            }
        }
        __syncthreads();

        const int tot = min((int)inc[NATOM - 1], BLKCAP2);
        float2* dstr = rec + (size_t)b * BLKCAP2;
        for (int i = tid; i < tot; i += 1024) dstr[i] = list[i];
        if (tid < NATOM) {
            cnt[((size_t)mol * NATOM + tid) * NSUB2 + sub] = lcnt[tid];
            soff_g[(size_t)b * NATOM + tid] = inc[tid] - lcnt[tid];
        }
        float* tg = tv_part + (size_t)b * NATOM * 3;
        for (int i = tid; i < NATOM * 3; i += 1024) tg[i] = tv_sc[i];
    }
}

// ---------------------------------------------------------------------------
// K2 gather: verbatim R21 (quadratic-exponent form).
// ---------------------------------------------------------------------------
__global__ __launch_bounds__(256) void gather_kernel(
    const unsigned* __restrict__ cnt, const unsigned* __restrict__ soff_g,
    const float2* __restrict__ rec,
    const float* __restrict__ centers, const float* __restrict__ widths,
    const float* __restrict__ c_emb, const float* __restrict__ tv_part,
    unsigned short* __restrict__ dens_bf, float* __restrict__ tvv)
{
    __shared__ float    cemb[8 * NB];
    __shared__ float2   list[ABLK][SLOTS];
    __shared__ unsigned scnt[ABLK][NSUB];
    __shared__ unsigned sofg[ABLK][NSUB];
    __shared__ unsigned soff[ABLK][NSUB];
    __shared__ unsigned mtot[ABLK];

    const int tid = threadIdx.x;
    const int a0  = blockIdx.x * ABLK;
    const int mol = a0 >> 9;
    const int ra0 = a0 & 511;

    for (int i = tid; i < 8 * NB; i += 256) cemb[i] = c_emb[i];
    if (tid < ABLK * NSUB) {
        const int al = tid >> 3, s = tid & 7;
        scnt[al][s] = cnt[(size_t)(a0 + al) * NSUB + s];
        sofg[al][s] = soff_g[(size_t)(mol * NSUB + s) * NATOM + (ra0 + al)];
    }
    __syncthreads();

    if (tid < ABLK) {
        int o = 0;
#pragma unroll
        for (int s = 0; s < NSUB; ++s) {
            soff[tid][s] = (unsigned)o;
            o += min((int)scnt[tid][s], SLOTS - o);
        }
        const int mp = (o + 7) & ~7;
        mtot[tid] = (unsigned)mp;
        for (int k = o; k < mp; ++k) list[tid][k] = make_float2(0.f, 0.f);
    }
    __syncthreads();

    {
        const int seg = tid >> 2;
        const int prt = tid & 3;
        const int al = seg >> 3, s = seg & 7;
        const int off = (int)soff[al][s];
        const int n = min((int)scnt[al][s], SLOTS - off);
        const float2* src = rec + (size_t)(mol * NSUB + s) * BLKCAP + sofg[al][s];
        float2* dst = &list[al][off];
        const int k0 = prt * 5, k1 = min(k0 + 5, n);
        for (int k = k0; k < k1; ++k) dst[k] = src[k];
    }
    if (tid < ABLK * 3) {
        const int al = tid / 3, c = tid - al * 3;
        float s = 0.f;
#pragma unroll
        for (int sb = 0; sb < NSUB; ++sb)
            s += tv_part[((size_t)(mol * NSUB + sb) * NATOM + (ra0 + al)) * 3 + c];
        tvv[(size_t)(a0 + al) * 3 + c] = s;
    }
    __syncthreads();

    const int lane = tid & 63;
    const int wave = tid >> 6;
    const float L2E = 1.4426950408889634f;
    const float wl  = widths[lane];
    const float cl  = centers[lane];
    const float e2  = -wl * L2E;
    const float b2  = 2.f * wl * cl * L2E;
    const float a2  = -wl * cl * cl * L2E;

#define REC1(A, dv, fv) { const unsigned f_ = __float_as_uint(fv);           \
        const float v_ = fmaf(dv, fmaf(dv, e2, b2), a2);                     \
        A = fmaf(exp2f(v_) * __uint_as_float(f_ & ~7u),                      \
                 cemb[((f_ & 7u) << 6) | lane], A); }

    for (int al = wave; al < ABLK; al += 4) {
        const int m = (int)mtot[al];
        const float4* l4 = reinterpret_cast<const float4*>(list[al]);
        float acc0 = 0.f, acc1 = 0.f;
        for (int j = 0; j < m; j += 8) {
            const float4 q0 = l4[(j >> 1) + 0];
            const float4 q1 = l4[(j >> 1) + 1];
            const float4 q2 = l4[(j >> 1) + 2];
            const float4 q3 = l4[(j >> 1) + 3];
            REC1(acc0, q0.x, q0.y) REC1(acc1, q0.z, q0.w)
            REC1(acc0, q1.x, q1.y) REC1(acc1, q1.z, q1.w)
            REC1(acc0, q2.x, q2.y) REC1(acc1, q2.z, q2.w)
            REC1(acc0, q3.x, q3.y) REC1(acc1, q3.z, q3.w)
        }
        dens_bf[(size_t)(a0 + al) * NB + lane] = f2bf(acc0 + acc1);
    }
#undef REC1
}

// ---------------------------------------------------------------------------
// K3 nn via MFMA: verbatim R21 (dipole atomics folded in).
// ---------------------------------------------------------------------------
__global__ __launch_bounds__(256) void nn_kernel(
    const unsigned short* __restrict__ dens_bf, const float* __restrict__ tvv,
    const float* __restrict__ W1, const float* __restrict__ b1,
    const float* __restrict__ W2, const float* __restrict__ b2,
    float* __restrict__ dipole)
{
    __shared__ __align__(16) unsigned short w1t[HIDDEN * 72];
    __shared__ float b1_l[HIDDEN], w2_l[HIDDEN];
    __shared__ float sred[4][4][3];

    const int tid = threadIdx.x;
    const int mol = blockIdx.x >> 3;

    for (int i = tid; i < NB * HIDDEN; i += 256) {
        const int k = i >> 8, j = i & 255;
        w1t[j * 72 + k] = f2bf(W1[i]);
    }
    if (tid < HIDDEN) { b1_l[tid] = b1[tid]; w2_l[tid] = W2[tid]; }
    __syncthreads();

    const int lane = tid & 63;
    const int wave = tid >> 6;
    const int fr   = lane & 15;
    const int fg   = lane >> 4;
    const int a0w  = blockIdx.x * 64 + wave * 16;

    bf16x8 afr[2];
#pragma unroll
    for (int kk = 0; kk < 2; ++kk)
        afr[kk] = *reinterpret_cast<const bf16x8*>(
            dens_bf + (size_t)(a0w + fr) * NB + kk * 32 + fg * 8);

    float sdip[4] = {0.f, 0.f, 0.f, 0.f};
#pragma unroll
    for (int nt = 0; nt < 16; ++nt) {
        const bf16x8 bf0 = *reinterpret_cast<const bf16x8*>(
            &w1t[(nt * 16 + fr) * 72 + 0 + fg * 8]);
        const bf16x8 bf1 = *reinterpret_cast<const bf16x8*>(
            &w1t[(nt * 16 + fr) * 72 + 32 + fg * 8]);
        f32x4 acc = {0.f, 0.f, 0.f, 0.f};
        acc = __builtin_amdgcn_mfma_f32_16x16x32_bf16(afr[0], bf0, acc, 0, 0, 0);
        acc = __builtin_amdgcn_mfma_f32_16x16x32_bf16(afr[1], bf1, acc, 0, 0, 0);
        const int j = nt * 16 + fr;
        const float b1v = b1_l[j], w2v = w2_l[j];
#pragma unroll
        for (int i = 0; i < 4; ++i) {
            const float h = acc[i] + b1v;
            sdip[i] += (h / (1.f + __expf(-h))) * w2v;
        }
    }
#pragma unroll
    for (int off = 1; off < 16; off <<= 1) {
#pragma unroll
        for (int i = 0; i < 4; ++i) sdip[i] += __shfl_xor(sdip[i], off);
    }
    if (fr == 0) {
        const float b2v = b2[0];
        float px = 0.f, py = 0.f, pz = 0.f;
#pragma unroll
        for (int i = 0; i < 4; ++i) {
            const int a = a0w + fg * 4 + i;
            const float out = sdip[i] + b2v;
            px += out * tvv[a * 3 + 0];
            py += out * tvv[a * 3 + 1];
            pz += out * tvv[a * 3 + 2];
        }
        sred[wave][fg][0] = px; sred[wave][fg][1] = py; sred[wave][fg][2] = pz;
    }
    __syncthreads();
    if (tid < 3) {
        float s = 0.f;
#pragma unroll
        for (int w = 0; w < 4; ++w)
#pragma unroll
            for (int g = 0; g < 4; ++g) s += sred[w][g][tid];
        unsafeAtomicAdd(&dipole[mol * 3 + tid], s);
    }
}

// ---------------------------------------------------------------------------
extern "C" void kernel_launch(void* const* d_in, const int* in_sizes, int n_in,
                              void* d_out, int out_size, void* d_ws, size_t ws_size,
                              hipStream_t stream)
{
    const float* cart       = (const float*)d_in[0];
    const float* shifts     = (const float*)d_in[1];
    const float* centers    = (const float*)d_in[2];
    const float* widths     = (const float*)d_in[3];
    const float* c_emb      = (const float*)d_in[4];
    const float* W1         = (const float*)d_in[5];
    const float* b1         = (const float*)d_in[6];
    const float* W2         = (const float*)d_in[7];
    const float* b2         = (const float*)d_in[8];
    const int*   species    = (const int*)d_in[10];
    const int*   atom_index = (const int*)d_in[11];

    // production ws: tv_part(1.5MB) | cnt(512KB) | soff_g(512KB) | tvv(192KB)
    //              | dens_bf(2MB) | rec(5MB)
    float*          tv_part = (float*)d_ws;
    unsigned*       cnt     = (unsigned*)(tv_part + (size_t)NMOL * NSUB * NATOM * 3);
    unsigned*       soff_g  = cnt + (size_t)TOTNATOM * NSUB;
    float*          tvv     = (float*)(soff_g + (size_t)NMOL * NSUB * NATOM);
    unsigned short* dens_bf = (unsigned short*)(tvv + (size_t)TOTNATOM * 3);
    float2*         rec     = (float2*)(dens_bf + (size_t)TOTNATOM * NB);
    // shadow scratch (disjoint): cnt2(1MB) | soff2(1MB) | tv2(3MB) | rec2(5.25MB)
    unsigned*       cnt2    = (unsigned*)(rec + (size_t)NMOL * NSUB * BLKCAP);
    unsigned*       soff2   = cnt2 + (size_t)TOTNATOM * NSUB2;
    float*          tv2     = (float*)(soff2 + (size_t)NMOL * NSUB2 * NATOM);
    float2*         rec2    = (float2*)(tv2 + (size_t)NMOL * NSUB2 * NATOM * 3);
    float*          dipole  = (float*)d_out;

    hipLaunchKernelGGL(scatter_kernel, dim3(NMOL * NSUB), dim3(1024), 0, stream,
                       cart, shifts, species, atom_index, cnt, soff_g, rec,
                       tv_part, dipole, out_size, SREP);
    hipLaunchKernelGGL(gather_kernel, dim3(TOTNATOM / ABLK), dim3(256), 0, stream,
                       cnt, soff_g, rec, centers, widths, c_emb, tv_part,
                       dens_bf, tvv);
    hipLaunchKernelGGL(nn_kernel, dim3(TOTNATOM / 64), dim3(256), 0, stream,
                       dens_bf, tvv, W1, b1, W2, b2, dipole);
    // shadow A/B probe (scratch only; after the real pipeline)
    hipLaunchKernelGGL(scatter16_kernel, dim3(NMOL * NSUB2), dim3(1024), 0, stream,
                       cart, shifts, species, atom_index, cnt2, soff2, rec2,
                       tv2, SREP);
}

// Round 23
// 53.292 us; speedup vs baseline: 6.5617x; 6.5617x over previous
//
#include <hip/hip_runtime.h>

#define NMOL   32
#define NATOM  512
#define NPAIR  32768
#define NB     64
#define HIDDEN 256
#define TOTNATOM (NMOL * NATOM)
#define NSUB   8
#define BLKCAP 2560
#define ABLK   8
#define SLOTS  128

typedef __attribute__((ext_vector_type(8))) short bf16x8;
typedef __attribute__((ext_vector_type(4))) float f32x4;

__device__ __forceinline__ unsigned short f2bf(float x) {   // RNE f32->bf16
    unsigned u = __float_as_uint(x);
    u += 0x7FFFu + ((u >> 16) & 1u);
    return (unsigned short)(u >> 16);
}

// ---------------------------------------------------------------------------
// K1 scatter. R23 (from R22's A/B: 20.6us/rep INVARIANT to occupancy, VALU 7%,
// conflicts negligible -> serial dependent-chain latency):
//  (a) pass 1 software-pipelined: all 4 iterations' global loads batched into
//      registers up-front, branchless mask-multiply body (no `continue`) so
//      the compiler overlaps the global->LDS-read->atomic chains.
//  (b) single-wave shuffle scan (4 block barriers instead of ~20).
// ---------------------------------------------------------------------------
__global__ __launch_bounds__(1024) void scatter_kernel(
    const float* __restrict__ cart, const float* __restrict__ shifts,
    const int* __restrict__ species, const int* __restrict__ atom_index,
    unsigned* __restrict__ cnt, unsigned* __restrict__ soff_g,
    float2* __restrict__ rec, float* __restrict__ tv_part,
    float* __restrict__ dipole, int ndip)
{
    __shared__ float    tv_sc[NATOM * 3];   // 6 KB
    __shared__ float    s_cart[NATOM * 3];  // 6 KB
    __shared__ int      s_sp[NATOM];        // 2 KB
    __shared__ unsigned lcnt[NATOM];        // 2 KB
    __shared__ unsigned pref[NATOM];        // 2 KB (exclusive offsets)
    __shared__ unsigned pcnt[NATOM];        // 2 KB (pass-2 cursors)
    __shared__ unsigned stot;
    __shared__ float2   list[BLKCAP];       // 20 KB

    const int tid  = threadIdx.x;
    const int lane = tid & 63;
    const int wave = tid >> 6;
    const int b    = blockIdx.x;
    const int mol  = b >> 3;
    const int sub  = b & 7;

    if (b == 0 && tid < ndip) dipole[tid] = 0.f;

    const float* cm = cart + (size_t)mol * NATOM * 3;
    const int*   sp = species + (size_t)mol * NATOM;
    for (int i = tid; i < NATOM * 3; i += 1024) { tv_sc[i] = 0.f; s_cart[i] = cm[i]; }
    if (tid < NATOM) { lcnt[tid] = 0u; pcnt[tid] = 0u; s_sp[tid] = sp[tid]; }
    __syncthreads();

    const int* ai0 = atom_index + (size_t)mol * NPAIR;
    const int* ai1 = ai0 + (size_t)NMOL * NPAIR;
    const float* sh = shifts + (size_t)mol * NPAIR * 3;
    const int base = sub * 4096;

    // ---- pass 1: batched loads, branchless mask body, pipelined ----
    int   gi0[4], gi1[4];
    float gsx[4], gsy[4], gsz[4];
#pragma unroll
    for (int k = 0; k < 4; ++k) {               // all global loads issued first
        const int p = base + k * 1024 + tid;
        gi0[k] = ai0[p];
        gi1[k] = ai1[p];
        gsx[k] = sh[p * 3 + 0];
        gsy[k] = sh[p * 3 + 1];
        gsz[k] = sh[p * 3 + 2];
    }

    float    rd[4];
    unsigned rf[4];
    int      ri[4];
#pragma unroll
    for (int k = 0; k < 4; ++k) {
        const int a3 = gi0[k] * 3, b3 = gi1[k] * 3;
        const float m = (gsx[k] > -1e10f && gsy[k] > -1e10f && gsz[k] > -1e10f)
                        ? 1.f : 0.f;
        const float dx = (s_cart[a3 + 0] - s_cart[b3 + 0] + gsx[k]) * m;
        const float dy = (s_cart[a3 + 1] - s_cart[b3 + 1] + gsy[k]) * m;
        const float dz = (s_cart[a3 + 2] - s_cart[b3 + 2] + gsz[k]) * m;
        unsafeAtomicAdd(&tv_sc[a3 + 0], dx);    // ds_add_f32 (0 for masked)
        unsafeAtomicAdd(&tv_sc[a3 + 1], dy);
        unsafeAtomicAdd(&tv_sc[a3 + 2], dz);
        const float d = sqrtf(dx * dx + dy * dy + dz * dz + 1e-12f);
        ri[k] = -1;
        if (d < 5.0f && m != 0.f) {             // masked pairs contribute nothing
            const float fc = 0.5f * (__cosf(0.62831853071795864769f * d) + 1.f);
            // pack spc into fc's low 3 mantissa bits (<=2^-20 rel perturbation)
            rd[k] = d;
            rf[k] = (__float_as_uint(fc) & ~7u) | (unsigned)s_sp[gi1[k]];
            ri[k] = gi0[k];
            atomicAdd(&lcnt[gi0[k]], 1u);       // LDS, native
        }
    }
    __syncthreads();

    // ---- single-wave exclusive scan of lcnt[512] (wave 0 only) ----
    if (wave == 0) {
        unsigned c[8], s = 0;
#pragma unroll
        for (int j = 0; j < 8; ++j) { c[j] = lcnt[lane * 8 + j]; s += c[j]; }
        unsigned incl = s;
#pragma unroll
        for (int off = 1; off < 64; off <<= 1) {
            const unsigned v = __shfl_up(incl, off);
            if (lane >= off) incl += v;
        }
        unsigned run = incl - s;                // exclusive lane base
#pragma unroll
        for (int j = 0; j < 8; ++j) { pref[lane * 8 + j] = run; run += c[j]; }
        if (lane == 63) stot = incl;            // grand total
    }
    __syncthreads();

    // ---- pass 2: place records atom-grouped in LDS ----
#pragma unroll
    for (int k = 0; k < 4; ++k) {
        if (ri[k] >= 0) {
            const unsigned pos = atomicAdd(&pcnt[ri[k]], 1u);
            const unsigned idx = pref[ri[k]] + pos;
            if (idx < (unsigned)BLKCAP)
                list[idx] = make_float2(rd[k], __uint_as_float(rf[k]));
        }
    }
    __syncthreads();

    // ---- coalesced sweep + metadata ----
    const int tot = min((int)stot, BLKCAP);
    float2* dstr = rec + (size_t)b * BLKCAP;
    for (int i = tid; i < tot; i += 1024) dstr[i] = list[i];

    if (tid < NATOM) {
        cnt[((size_t)mol * NATOM + tid) * NSUB + sub] = lcnt[tid];
        soff_g[(size_t)b * NATOM + tid] = pref[tid];
    }
    float* tg = tv_part + (size_t)b * NATOM * 3;
    for (int i = tid; i < NATOM * 3; i += 1024) tg[i] = tv_sc[i];
}

// ---------------------------------------------------------------------------
// K2 gather: verbatim R21 (quadratic-exponent form; measured ~14us, VALU 75%).
// ---------------------------------------------------------------------------
__global__ __launch_bounds__(256) void gather_kernel(
    const unsigned* __restrict__ cnt, const unsigned* __restrict__ soff_g,
    const float2* __restrict__ rec,
    const float* __restrict__ centers, const float* __restrict__ widths,
    const float* __restrict__ c_emb, const float* __restrict__ tv_part,
    unsigned short* __restrict__ dens_bf, float* __restrict__ tvv)
{
    __shared__ float    cemb[8 * NB];
    __shared__ float2   list[ABLK][SLOTS];
    __shared__ unsigned scnt[ABLK][NSUB];
    __shared__ unsigned sofg[ABLK][NSUB];
    __shared__ unsigned soff[ABLK][NSUB];
    __shared__ unsigned mtot[ABLK];

    const int tid = threadIdx.x;
    const int a0  = blockIdx.x * ABLK;
    const int mol = a0 >> 9;
    const int ra0 = a0 & 511;

    for (int i = tid; i < 8 * NB; i += 256) cemb[i] = c_emb[i];
    if (tid < ABLK * NSUB) {
        const int al = tid >> 3, s = tid & 7;
        scnt[al][s] = cnt[(size_t)(a0 + al) * NSUB + s];
        sofg[al][s] = soff_g[(size_t)(mol * NSUB + s) * NATOM + (ra0 + al)];
    }
    __syncthreads();

    if (tid < ABLK) {
        int o = 0;
#pragma unroll
        for (int s = 0; s < NSUB; ++s) {
            soff[tid][s] = (unsigned)o;
            o += min((int)scnt[tid][s], SLOTS - o);
        }
        const int mp = (o + 7) & ~7;
        mtot[tid] = (unsigned)mp;
        for (int k = o; k < mp; ++k) list[tid][k] = make_float2(0.f, 0.f);
    }
    __syncthreads();

    {
        const int seg = tid >> 2;
        const int prt = tid & 3;
        const int al = seg >> 3, s = seg & 7;
        const int off = (int)soff[al][s];
        const int n = min((int)scnt[al][s], SLOTS - off);
        const float2* src = rec + (size_t)(mol * NSUB + s) * BLKCAP + sofg[al][s];
        float2* dst = &list[al][off];
        const int k0 = prt * 5, k1 = min(k0 + 5, n);
        for (int k = k0; k < k1; ++k) dst[k] = src[k];
    }
    if (tid < ABLK * 3) {
        const int al = tid / 3, c = tid - al * 3;
        float s = 0.f;
#pragma unroll
        for (int sb = 0; sb < NSUB; ++sb)
            s += tv_part[((size_t)(mol * NSUB + sb) * NATOM + (ra0 + al)) * 3 + c];
        tvv[(size_t)(a0 + al) * 3 + c] = s;
    }
    __syncthreads();

    const int lane = tid & 63;
    const int wave = tid >> 6;
    const float L2E = 1.4426950408889634f;
    const float wl  = widths[lane];
    const float cl  = centers[lane];
    const float e2  = -wl * L2E;
    const float b2  = 2.f * wl * cl * L2E;
    const float a2  = -wl * cl * cl * L2E;

#define REC1(A, dv, fv) { const unsigned f_ = __float_as_uint(fv);           \
        const float v_ = fmaf(dv, fmaf(dv, e2, b2), a2);                     \
        A = fmaf(exp2f(v_) * __uint_as_float(f_ & ~7u),                      \
                 cemb[((f_ & 7u) << 6) | lane], A); }

    for (int al = wave; al < ABLK; al += 4) {
        const int m = (int)mtot[al];
        const float4* l4 = reinterpret_cast<const float4*>(list[al]);
        float acc0 = 0.f, acc1 = 0.f;
        for (int j = 0; j < m; j += 8) {
            const float4 q0 = l4[(j >> 1) + 0];
            const float4 q1 = l4[(j >> 1) + 1];
            const float4 q2 = l4[(j >> 1) + 2];
            const float4 q3 = l4[(j >> 1) + 3];
            REC1(acc0, q0.x, q0.y) REC1(acc1, q0.z, q0.w)
            REC1(acc0, q1.x, q1.y) REC1(acc1, q1.z, q1.w)
            REC1(acc0, q2.x, q2.y) REC1(acc1, q2.z, q2.w)
            REC1(acc0, q3.x, q3.y) REC1(acc1, q3.z, q3.w)
        }
        dens_bf[(size_t)(a0 + al) * NB + lane] = f2bf(acc0 + acc1);
    }
#undef REC1
}

// ---------------------------------------------------------------------------
// K3 nn via MFMA: verbatim R21 (dipole atomics folded in).
// ---------------------------------------------------------------------------
__global__ __launch_bounds__(256) void nn_kernel(
    const unsigned short* __restrict__ dens_bf, const float* __restrict__ tvv,
    const float* __restrict__ W1, const float* __restrict__ b1,
    const float* __restrict__ W2, const float* __restrict__ b2,
    float* __restrict__ dipole)
{
    __shared__ __align__(16) unsigned short w1t[HIDDEN * 72];
    __shared__ float b1_l[HIDDEN], w2_l[HIDDEN];
    __shared__ float sred[4][4][3];

    const int tid = threadIdx.x;
    const int mol = blockIdx.x >> 3;

    for (int i = tid; i < NB * HIDDEN; i += 256) {
        const int k = i >> 8, j = i & 255;
        w1t[j * 72 + k] = f2bf(W1[i]);
    }
    if (tid < HIDDEN) { b1_l[tid] = b1[tid]; w2_l[tid] = W2[tid]; }
    __syncthreads();

    const int lane = tid & 63;
    const int wave = tid >> 6;
    const int fr   = lane & 15;
    const int fg   = lane >> 4;
    const int a0w  = blockIdx.x * 64 + wave * 16;

    bf16x8 afr[2];
#pragma unroll
    for (int kk = 0; kk < 2; ++kk)
        afr[kk] = *reinterpret_cast<const bf16x8*>(
            dens_bf + (size_t)(a0w + fr) * NB + kk * 32 + fg * 8);

    float sdip[4] = {0.f, 0.f, 0.f, 0.f};
#pragma unroll
    for (int nt = 0; nt < 16; ++nt) {
        const bf16x8 bf0 = *reinterpret_cast<const bf16x8*>(
            &w1t[(nt * 16 + fr) * 72 + 0 + fg * 8]);
        const bf16x8 bf1 = *reinterpret_cast<const bf16x8*>(
            &w1t[(nt * 16 + fr) * 72 + 32 + fg * 8]);
        f32x4 acc = {0.f, 0.f, 0.f, 0.f};
        acc = __builtin_amdgcn_mfma_f32_16x16x32_bf16(afr[0], bf0, acc, 0, 0, 0);
        acc = __builtin_amdgcn_mfma_f32_16x16x32_bf16(afr[1], bf1, acc, 0, 0, 0);
        const int j = nt * 16 + fr;
        const float b1v = b1_l[j], w2v = w2_l[j];
#pragma unroll
        for (int i = 0; i < 4; ++i) {
            const float h = acc[i] + b1v;
            sdip[i] += (h / (1.f + __expf(-h))) * w2v;
        }
    }
#pragma unroll
    for (int off = 1; off < 16; off <<= 1) {
#pragma unroll
        for (int i = 0; i < 4; ++i) sdip[i] += __shfl_xor(sdip[i], off);
    }
    if (fr == 0) {
        const float b2v = b2[0];
        float px = 0.f, py = 0.f, pz = 0.f;
#pragma unroll
        for (int i = 0; i < 4; ++i) {
            const int a = a0w + fg * 4 + i;
            const float out = sdip[i] + b2v;
            px += out * tvv[a * 3 + 0];
            py += out * tvv[a * 3 + 1];
            pz += out * tvv[a * 3 + 2];
        }
        sred[wave][fg][0] = px; sred[wave][fg][1] = py; sred[wave][fg][2] = pz;
    }
    __syncthreads();
    if (tid < 3) {
        float s = 0.f;
#pragma unroll
        for (int w = 0; w < 4; ++w)
#pragma unroll
            for (int g = 0; g < 4; ++g) s += sred[w][g][tid];
        unsafeAtomicAdd(&dipole[mol * 3 + tid], s);
    }
}

// ---------------------------------------------------------------------------
extern "C" void kernel_launch(void* const* d_in, const int* in_sizes, int n_in,
                              void* d_out, int out_size, void* d_ws, size_t ws_size,
                              hipStream_t stream)
{
    const float* cart       = (const float*)d_in[0];
    const float* shifts     = (const float*)d_in[1];
    const float* centers    = (const float*)d_in[2];
    const float* widths     = (const float*)d_in[3];
    const float* c_emb      = (const float*)d_in[4];
    const float* W1         = (const float*)d_in[5];
    const float* b1         = (const float*)d_in[6];
    const float* W2         = (const float*)d_in[7];
    const float* b2         = (const float*)d_in[8];
    const int*   species    = (const int*)d_in[10];
    const int*   atom_index = (const int*)d_in[11];

    // ws: tv_part(1.5MB) | cnt(512KB) | soff_g(512KB) | tvv(192KB) |
    //     dens_bf(2MB) | rec(5MB)
    float*          tv_part = (float*)d_ws;
    unsigned*       cnt     = (unsigned*)(tv_part + (size_t)NMOL * NSUB * NATOM * 3);
    unsigned*       soff_g  = cnt + (size_t)TOTNATOM * NSUB;
    float*          tvv     = (float*)(soff_g + (size_t)NMOL * NSUB * NATOM);
    unsigned short* dens_bf = (unsigned short*)(tvv + (size_t)TOTNATOM * 3);
    float2*         rec     = (float2*)(dens_bf + (size_t)TOTNATOM * NB);
    float*          dipole  = (float*)d_out;

    hipLaunchKernelGGL(scatter_kernel, dim3(NMOL * NSUB), dim3(1024), 0, stream,
                       cart, shifts, species, atom_index, cnt, soff_g, rec,
                       tv_part, dipole, out_size);
    hipLaunchKernelGGL(gather_kernel, dim3(TOTNATOM / ABLK), dim3(256), 0, stream,
                       cnt, soff_g, rec, centers, widths, c_emb, tv_part,
                       dens_bf, tvv);
    hipLaunchKernelGGL(nn_kernel, dim3(TOTNATOM / 64), dim3(256), 0, stream,
                       dens_bf, tvv, W1, b1, W2, b2, dipole);
}